// Round 1
// baseline (698.681 us; speedup 1.0000x reference)
//
#include <hip/hip_runtime.h>
#include <math.h>

// Problem constants
#define TB 2
#define TT 31
#define TH 160
#define TW 160
#define THW (TH*TW)            // 25600
#define NPER (TB*TT*THW)       // 1,587,200 elements per channel
#define HCN 16                 // hidden channels

// Workspace layout (in floats)
#define H_ELEMS (TB*HCN*TT*THW)          // 25,395,200 floats (101.6 MB)
#define C2_OFF  H_ELEMS
#define C3_OFF  (C2_OFF + NPER)
#define S1_OFF  (C3_OFF + NPER)          // 64: sum[32], sumsq[32]
#define AB1_OFF (S1_OFF + 64)            // 64: a[32], b[32]
#define S2_OFF  (AB1_OFF + 64)           // 4: sum2,sumsq2,sum3,sumsq3
#define AB2_OFF (S2_OFF + 4)             // 4: a2,b2,a3,b3

// ---------- helpers ----------

__device__ __forceinline__ void load_plane(float p[9], const float* __restrict__ in,
                                           int b, int t, int y, int x) {
    #pragma unroll
    for (int ky = 0; ky < 3; ++ky) {
        int yy = y + ky - 1;
        #pragma unroll
        for (int kx = 0; kx < 3; ++kx) {
            int xx = x + kx - 1;
            float v = 0.f;
            if (t >= 0 && t < TT && yy >= 0 && yy < TH && xx >= 0 && xx < TW)
                v = in[((b*TT + t)*TH + yy)*TW + xx];
            p[ky*3 + kx] = v;
        }
    }
}

__device__ __forceinline__ float conv27(const float w[27], const float pm[9],
                                        const float pc[9], const float pn[9]) {
    float s = 0.f;
    #pragma unroll
    for (int i = 0; i < 9; ++i) s = fmaf(w[i],      pm[i], s);
    #pragma unroll
    for (int i = 0; i < 9; ++i) s = fmaf(w[9 + i],  pc[i], s);
    #pragma unroll
    for (int i = 0; i < 9; ++i) s = fmaf(w[18 + i], pn[i], s);
    return s;
}

__device__ __forceinline__ float sigmoidf_(float x) {
    return 1.f / (1.f + expf(-x));
}

// ---------- kernel 1: conv1 per-channel sum/sumsq (no store) ----------
// grid: (100, 32, 2), block 256.  Each thread: one (b, c, y, x), loops t.
__global__ __launch_bounds__(256)
void k1_gates_stats(const float* __restrict__ in, const float* __restrict__ wg,
                    float* __restrict__ stats) {
    int b = blockIdx.z, c = blockIdx.y;
    int p = blockIdx.x * blockDim.x + threadIdx.x;
    int y = p / TW, x = p % TW;

    float wc[27];
    #pragma unroll
    for (int i = 0; i < 27; ++i) wc[i] = wg[c*27 + i];

    float pm[9], pc_[9], pn[9];
    load_plane(pm,  in, b, -1, y, x);   // zeros
    load_plane(pc_, in, b,  0, y, x);

    float s = 0.f, sq = 0.f;
    for (int t = 0; t < TT; ++t) {
        load_plane(pn, in, b, t + 1, y, x);     // zeros at t==TT-1
        float v = conv27(wc, pm, pc_, pn);
        s += v; sq += v*v;
        #pragma unroll
        for (int i = 0; i < 9; ++i) { pm[i] = pc_[i]; pc_[i] = pn[i]; }
    }

    // block reduce
    #pragma unroll
    for (int off = 32; off > 0; off >>= 1) {
        s  += __shfl_down(s,  off, 64);
        sq += __shfl_down(sq, off, 64);
    }
    __shared__ float ls[4], lq[4];
    int lane = threadIdx.x & 63, wid = threadIdx.x >> 6;
    if (lane == 0) { ls[wid] = s; lq[wid] = sq; }
    __syncthreads();
    if (threadIdx.x == 0) {
        atomicAdd(&stats[c],      ls[0]+ls[1]+ls[2]+ls[3]);
        atomicAdd(&stats[32 + c], lq[0]+lq[1]+lq[2]+lq[3]);
    }
}

// ---------- kernel 2: finalize gate BN params ----------
__global__ void k2_fin1(const float* __restrict__ stats, const float* __restrict__ gamma,
                        const float* __restrict__ beta, float* __restrict__ ab) {
    int c = threadIdx.x;
    if (c < 32) {
        float n = (float)NPER;
        float mean = stats[c] / n;
        float var  = stats[32 + c] / n - mean*mean;
        float a = gamma[c] * rsqrtf(var + 1e-5f);
        ab[c]      = a;
        ab[32 + c] = beta[c] - mean * a;
    }
}

// ---------- kernel 3: recompute conv1, normalize, activate, scan, store h ----------
// grid: (100, 16, 2), block 256. Thread: one (b, c, y, x), scans over t.
__global__ __launch_bounds__(256)
void k3_scan(const float* __restrict__ in, const float* __restrict__ wg,
             const float* __restrict__ ab, const int* __restrict__ rev_p,
             float* __restrict__ hbuf) {
    int b = blockIdx.z, c = blockIdx.y;
    int p = blockIdx.x * blockDim.x + threadIdx.x;
    int y = p / TW, x = p % TW;

    float wz[27], wf[27];
    #pragma unroll
    for (int i = 0; i < 27; ++i) { wz[i] = wg[c*27 + i]; wf[i] = wg[(c + 16)*27 + i]; }
    float az = ab[c],      bz = ab[32 + c];
    float af = ab[c + 16], bf = ab[32 + c + 16];
    int rev = rev_p[0];

    float h = 0.f;
    float pm[9], pc_[9], pn[9];
    long hbase = ((long)(b*HCN + c)) * TT * THW + p;

    if (!rev) {
        load_plane(pm,  in, b, -1, y, x);
        load_plane(pc_, in, b,  0, y, x);
        for (int t = 0; t < TT; ++t) {
            load_plane(pn, in, b, t + 1, y, x);
            float z = tanhf(fmaf(az, conv27(wz, pm, pc_, pn), bz));
            float f = sigmoidf_(fmaf(af, conv27(wf, pm, pc_, pn), bf));
            h = f*h + (1.f - f)*z;
            hbuf[hbase + (long)t * THW] = h;
            #pragma unroll
            for (int i = 0; i < 9; ++i) { pm[i] = pc_[i]; pc_[i] = pn[i]; }
        }
    } else {
        load_plane(pn,  in, b, TT,     y, x);  // zeros
        load_plane(pc_, in, b, TT - 1, y, x);
        for (int t = TT - 1; t >= 0; --t) {
            load_plane(pm, in, b, t - 1, y, x);
            float z = tanhf(fmaf(az, conv27(wz, pm, pc_, pn), bz));
            float f = sigmoidf_(fmaf(af, conv27(wf, pm, pc_, pn), bf));
            h = f*h + (1.f - f)*z;
            hbuf[hbase + (long)t * THW] = h;
            #pragma unroll
            for (int i = 0; i < 9; ++i) { pn[i] = pc_[i]; pc_[i] = pm[i]; }
        }
    }
}

// ---------- kernel 4: conv2 (h[0:8] -> scale raw) + conv3 (h[8:16] -> shift raw) + stats ----------
// grid: (100, 31, 2), block 256. Thread: one (b, t, y, x).
__global__ __launch_bounds__(256)
void k4_conv23(const float* __restrict__ hbuf, const float* __restrict__ wsc,
               const float* __restrict__ wsh, float* __restrict__ c2,
               float* __restrict__ c3, float* __restrict__ stats2) {
    int b = blockIdx.z, t = blockIdx.y;
    int p = blockIdx.x * blockDim.x + threadIdx.x;
    int y = p / TW, x = p % TW;

    float a2 = 0.f, a3 = 0.f;
    for (int c = 0; c < 8; ++c) {
        long base2 = ((long)(b*HCN + c))     * TT * THW;
        long base3 = ((long)(b*HCN + 8 + c)) * TT * THW;
        #pragma unroll
        for (int kt = 0; kt < 3; ++kt) {
            int tt = t + kt - 1;
            if (tt < 0 || tt >= TT) continue;
            #pragma unroll
            for (int ky = 0; ky < 3; ++ky) {
                int yy = y + ky - 1;
                if (yy < 0 || yy >= TH) continue;
                #pragma unroll
                for (int kx = 0; kx < 3; ++kx) {
                    int xx = x + kx - 1;
                    if (xx < 0 || xx >= TW) continue;
                    int widx = c*27 + kt*9 + ky*3 + kx;
                    long off = (long)tt * THW + yy*TW + xx;
                    a2 = fmaf(wsc[widx], hbuf[base2 + off], a2);
                    a3 = fmaf(wsh[widx], hbuf[base3 + off], a3);
                }
            }
        }
    }
    long oidx = ((long)(b*TT + t)) * THW + p;
    c2[oidx] = a2;
    c3[oidx] = a3;

    // block reduce 4 values
    float v0 = a2, v1 = a2*a2, v2 = a3, v3 = a3*a3;
    #pragma unroll
    for (int off = 32; off > 0; off >>= 1) {
        v0 += __shfl_down(v0, off, 64);
        v1 += __shfl_down(v1, off, 64);
        v2 += __shfl_down(v2, off, 64);
        v3 += __shfl_down(v3, off, 64);
    }
    __shared__ float red[4][4];
    int lane = threadIdx.x & 63, wid = threadIdx.x >> 6;
    if (lane == 0) { red[0][wid] = v0; red[1][wid] = v1; red[2][wid] = v2; red[3][wid] = v3; }
    __syncthreads();
    if (threadIdx.x == 0) {
        #pragma unroll
        for (int j = 0; j < 4; ++j)
            atomicAdd(&stats2[j], red[j][0] + red[j][1] + red[j][2] + red[j][3]);
    }
}

// ---------- kernel 5: finalize scale/shift BN params ----------
__global__ void k5_fin2(const float* __restrict__ stats2,
                        const float* __restrict__ gs, const float* __restrict__ bs,
                        const float* __restrict__ gt, const float* __restrict__ bt,
                        float* __restrict__ ab2) {
    if (threadIdx.x == 0) {
        float n = (float)NPER;
        float m2 = stats2[0] / n, v2 = stats2[1] / n - m2*m2;
        float a2 = gs[0] * rsqrtf(v2 + 1e-5f);
        ab2[0] = a2; ab2[1] = bs[0] - m2*a2;
        float m3 = stats2[2] / n, v3 = stats2[3] / n - m3*m3;
        float a3 = gt[0] * rsqrtf(v3 + 1e-5f);
        ab2[2] = a3; ab2[3] = bt[0] - m3*a3;
    }
}

// ---------- kernel 6: epilogue ----------
__global__ __launch_bounds__(256)
void k6_final(const float* __restrict__ c2, const float* __restrict__ c3,
              const float* __restrict__ ab2, float* __restrict__ out) {
    int i = blockIdx.x * blockDim.x + threadIdx.x;
    if (i < NPER) {
        float ls = fmaf(ab2[0], c2[i], ab2[1]);
        out[i] = sigmoidf_(ls + 2.f) + 1e-4f;                 // scale
        out[NPER + i] = fmaf(ab2[2], c3[i], ab2[3]);          // shift
    }
}

// ---------- launch ----------
extern "C" void kernel_launch(void* const* d_in, const int* in_sizes, int n_in,
                              void* d_out, int out_size, void* d_ws, size_t ws_size,
                              hipStream_t stream) {
    const float* in          = (const float*)d_in[0];
    const float* w_gate      = (const float*)d_in[1];
    const float* gamma_gate  = (const float*)d_in[2];
    const float* beta_gate   = (const float*)d_in[3];
    const float* w_scale     = (const float*)d_in[4];
    const float* gamma_scale = (const float*)d_in[5];
    const float* beta_scale  = (const float*)d_in[6];
    const float* w_shift     = (const float*)d_in[7];
    const float* gamma_shift = (const float*)d_in[8];
    const float* beta_shift  = (const float*)d_in[9];
    const int*   rev         = (const int*)d_in[10];

    float* ws   = (float*)d_ws;
    float* hbuf = ws;
    float* c2   = ws + C2_OFF;
    float* c3   = ws + C3_OFF;
    float* s1   = ws + S1_OFF;
    float* ab1  = ws + AB1_OFF;
    float* s2   = ws + S2_OFF;
    float* ab2  = ws + AB2_OFF;
    float* out  = (float*)d_out;

    // zero the stats/param scratch (ws is poisoned 0xAA before each launch)
    hipMemsetAsync(s1, 0, (64 + 64 + 4 + 4) * sizeof(float), stream);

    k1_gates_stats<<<dim3(THW/256, 32, TB), 256, 0, stream>>>(in, w_gate, s1);
    k2_fin1<<<1, 32, 0, stream>>>(s1, gamma_gate, beta_gate, ab1);
    k3_scan<<<dim3(THW/256, HCN, TB), 256, 0, stream>>>(in, w_gate, ab1, rev, hbuf);
    k4_conv23<<<dim3(THW/256, TT, TB), 256, 0, stream>>>(hbuf, w_scale, w_shift, c2, c3, s2);
    k5_fin2<<<1, 64, 0, stream>>>(s2, gamma_scale, beta_scale, gamma_shift, beta_shift, ab2);
    k6_final<<<(NPER + 255)/256, 256, 0, stream>>>(c2, c3, ab2, out);
}

// Round 2
// 414.393 us; speedup vs baseline: 1.6860x; 1.6860x over previous
//
#include <hip/hip_runtime.h>
#include <math.h>

// Problem constants
#define TB 2
#define TT 31
#define TH 160
#define TW 160
#define THW (TH*TW)            // 25600
#define NPER (TB*TT*THW)       // 1,587,200 elements per channel
#define HCN 16                 // hidden channels
#define TCH 8                  // t-chunk size for k4

// Workspace layout (in floats)
#define H_ELEMS (TB*HCN*TT*THW)          // 25,395,200 floats (101.6 MB)
#define C2_OFF  H_ELEMS
#define C3_OFF  (C2_OFF + NPER)
#define S1_OFF  (C3_OFF + NPER)          // 64: sum[32], sumsq[32]
#define AB1_OFF (S1_OFF + 64)            // 64: a[32], b[32]
#define S2_OFF  (AB1_OFF + 64)           // 4: sum2,sumsq2,sum3,sumsq3
#define AB2_OFF (S2_OFF + 4)             // 4: a2,b2,a3,b3

// ---------- helpers ----------

__device__ __forceinline__ void load_plane(float p[9], const float* __restrict__ in,
                                           int b, int t, int y, int x) {
    #pragma unroll
    for (int ky = 0; ky < 3; ++ky) {
        int yy = y + ky - 1;
        #pragma unroll
        for (int kx = 0; kx < 3; ++kx) {
            int xx = x + kx - 1;
            float v = 0.f;
            if (t >= 0 && t < TT && yy >= 0 && yy < TH && xx >= 0 && xx < TW)
                v = in[((b*TT + t)*TH + yy)*TW + xx];
            p[ky*3 + kx] = v;
        }
    }
}

__device__ __forceinline__ float conv27(const float w[27], const float pm[9],
                                        const float pc[9], const float pn[9]) {
    float s = 0.f;
    #pragma unroll
    for (int i = 0; i < 9; ++i) s = fmaf(w[i],      pm[i], s);
    #pragma unroll
    for (int i = 0; i < 9; ++i) s = fmaf(w[9 + i],  pc[i], s);
    #pragma unroll
    for (int i = 0; i < 9; ++i) s = fmaf(w[18 + i], pn[i], s);
    return s;
}

__device__ __forceinline__ float sigmoidf_(float x) {
    return 1.f / (1.f + expf(-x));
}

// ---------- kernel 1: conv1 per-channel sum/sumsq (no store) ----------
__global__ __launch_bounds__(256)
void k1_gates_stats(const float* __restrict__ in, const float* __restrict__ wg,
                    float* __restrict__ stats) {
    int b = blockIdx.z, c = blockIdx.y;
    int p = blockIdx.x * blockDim.x + threadIdx.x;
    int y = p / TW, x = p % TW;

    float wc[27];
    #pragma unroll
    for (int i = 0; i < 27; ++i) wc[i] = wg[c*27 + i];

    float pm[9], pc_[9], pn[9];
    load_plane(pm,  in, b, -1, y, x);   // zeros
    load_plane(pc_, in, b,  0, y, x);

    float s = 0.f, sq = 0.f;
    for (int t = 0; t < TT; ++t) {
        load_plane(pn, in, b, t + 1, y, x);     // zeros at t==TT-1
        float v = conv27(wc, pm, pc_, pn);
        s += v; sq += v*v;
        #pragma unroll
        for (int i = 0; i < 9; ++i) { pm[i] = pc_[i]; pc_[i] = pn[i]; }
    }

    #pragma unroll
    for (int off = 32; off > 0; off >>= 1) {
        s  += __shfl_down(s,  off, 64);
        sq += __shfl_down(sq, off, 64);
    }
    __shared__ float ls[4], lq[4];
    int lane = threadIdx.x & 63, wid = threadIdx.x >> 6;
    if (lane == 0) { ls[wid] = s; lq[wid] = sq; }
    __syncthreads();
    if (threadIdx.x == 0) {
        atomicAdd(&stats[c],      ls[0]+ls[1]+ls[2]+ls[3]);
        atomicAdd(&stats[32 + c], lq[0]+lq[1]+lq[2]+lq[3]);
    }
}

// ---------- kernel 2: finalize gate BN params ----------
__global__ void k2_fin1(const float* __restrict__ stats, const float* __restrict__ gamma,
                        const float* __restrict__ beta, float* __restrict__ ab) {
    int c = threadIdx.x;
    if (c < 32) {
        float n = (float)NPER;
        float mean = stats[c] / n;
        float var  = stats[32 + c] / n - mean*mean;
        float a = gamma[c] * rsqrtf(var + 1e-5f);
        ab[c]      = a;
        ab[32 + c] = beta[c] - mean * a;
    }
}

// ---------- kernel 3: recompute conv1, normalize, activate, scan, store h ----------
__global__ __launch_bounds__(256)
void k3_scan(const float* __restrict__ in, const float* __restrict__ wg,
             const float* __restrict__ ab, const int* __restrict__ rev_p,
             float* __restrict__ hbuf) {
    int b = blockIdx.z, c = blockIdx.y;
    int p = blockIdx.x * blockDim.x + threadIdx.x;
    int y = p / TW, x = p % TW;

    float wz[27], wf[27];
    #pragma unroll
    for (int i = 0; i < 27; ++i) { wz[i] = wg[c*27 + i]; wf[i] = wg[(c + 16)*27 + i]; }
    float az = ab[c],      bz = ab[32 + c];
    float af = ab[c + 16], bf = ab[32 + c + 16];
    int rev = rev_p[0];

    float h = 0.f;
    float pm[9], pc_[9], pn[9];
    long hbase = ((long)(b*HCN + c)) * TT * THW + p;

    if (!rev) {
        load_plane(pm,  in, b, -1, y, x);
        load_plane(pc_, in, b,  0, y, x);
        for (int t = 0; t < TT; ++t) {
            load_plane(pn, in, b, t + 1, y, x);
            float z = tanhf(fmaf(az, conv27(wz, pm, pc_, pn), bz));
            float f = sigmoidf_(fmaf(af, conv27(wf, pm, pc_, pn), bf));
            h = f*h + (1.f - f)*z;
            hbuf[hbase + (long)t * THW] = h;
            #pragma unroll
            for (int i = 0; i < 9; ++i) { pm[i] = pc_[i]; pc_[i] = pn[i]; }
        }
    } else {
        load_plane(pn,  in, b, TT,     y, x);  // zeros
        load_plane(pc_, in, b, TT - 1, y, x);
        for (int t = TT - 1; t >= 0; --t) {
            load_plane(pm, in, b, t - 1, y, x);
            float z = tanhf(fmaf(az, conv27(wz, pm, pc_, pn), bz));
            float f = sigmoidf_(fmaf(af, conv27(wf, pm, pc_, pn), bf));
            h = f*h + (1.f - f)*z;
            hbuf[hbase + (long)t * THW] = h;
            #pragma unroll
            for (int i = 0; i < 9; ++i) { pn[i] = pc_[i]; pc_[i] = pm[i]; }
        }
    }
}

// ---------- kernel 4: LDS-tiled conv2+conv3 over h, streaming (c, t_in) planes ----------
// grid: (100 tiles, 4 t-chunks, 2 b), block 256 = 16x16 tile.
__global__ __launch_bounds__(256)
void k4_conv23(const float* __restrict__ hbuf, const float* __restrict__ wsc,
               const float* __restrict__ wsh, float* __restrict__ c2,
               float* __restrict__ c3, float* __restrict__ stats2) {
    __shared__ float pl2[18*18];
    __shared__ float pl3[18*18];

    int b  = blockIdx.z;
    int t0 = blockIdx.y * TCH;
    int t1 = min(t0 + TCH - 1, TT - 1);
    int tile = blockIdx.x;
    int ty0 = (tile / 10) * 16, tx0 = (tile % 10) * 16;
    int tid = threadIdx.x;
    int ly = tid >> 4, lx = tid & 15;
    int y = ty0 + ly, x = tx0 + lx;

    int ts = max(t0 - 1, 0), te = min(t1 + 1, TT - 1);

    float accP2 = 0.f, accC2 = 0.f, accN2 = 0.f;
    float accP3 = 0.f, accC3 = 0.f, accN3 = 0.f;
    float s2l = 0.f, q2l = 0.f, s3l = 0.f, q3l = 0.f;

    for (int t_in = ts; t_in <= te; ++t_in) {
        for (int c = 0; c < 8; ++c) {
            __syncthreads();  // protect previous iteration's tap reads
            long base2 = ((long)((b*HCN + c)*TT + t_in)) * THW;
            long base3 = ((long)((b*HCN + 8 + c)*TT + t_in)) * THW;
            for (int i = tid; i < 18*18; i += 256) {
                int py = i / 18, px = i % 18;
                int gy = ty0 + py - 1, gx = tx0 + px - 1;
                bool ok = (gy >= 0 && gy < TH && gx >= 0 && gx < TW);
                long off = (long)gy * TW + gx;
                pl2[i] = ok ? hbuf[base2 + off] : 0.f;
                pl3[i] = ok ? hbuf[base3 + off] : 0.f;
            }
            __syncthreads();

            float t2[9], t3[9];
            #pragma unroll
            for (int ky = 0; ky < 3; ++ky)
                #pragma unroll
                for (int kx = 0; kx < 3; ++kx) {
                    int li = (ly + ky)*18 + (lx + kx);
                    t2[ky*3 + kx] = pl2[li];
                    t3[ky*3 + kx] = pl3[li];
                }
            const float* w2 = wsc + c*27;
            const float* w3 = wsh + c*27;
            // plane t_in contributes: kt=0 -> out t_in+1 (N), kt=1 -> out t_in (C), kt=2 -> out t_in-1 (P)
            #pragma unroll
            for (int i = 0; i < 9; ++i) {
                accN2 = fmaf(w2[i],      t2[i], accN2);
                accC2 = fmaf(w2[9 + i],  t2[i], accC2);
                accP2 = fmaf(w2[18 + i], t2[i], accP2);
                accN3 = fmaf(w3[i],      t3[i], accN3);
                accC3 = fmaf(w3[9 + i],  t3[i], accC3);
                accP3 = fmaf(w3[18 + i], t3[i], accP3);
            }
        }
        // output t_out = t_in - 1 is now complete
        int t_out = t_in - 1;
        if (t_out >= t0 && t_out <= t1) {
            long oidx = ((long)(b*TT + t_out)) * THW + (long)y*TW + x;
            c2[oidx] = accP2; c3[oidx] = accP3;
            s2l += accP2; q2l += accP2*accP2;
            s3l += accP3; q3l += accP3*accP3;
        }
        accP2 = accC2; accC2 = accN2; accN2 = 0.f;
        accP3 = accC3; accC3 = accN3; accN3 = 0.f;
    }
    // if this chunk owns t = TT-1, its output completes after t_in = TT-1 (zero pad beyond)
    if (t1 == TT - 1) {
        long oidx = ((long)(b*TT + (TT - 1))) * THW + (long)y*TW + x;
        c2[oidx] = accP2; c3[oidx] = accP3;
        s2l += accP2; q2l += accP2*accP2;
        s3l += accP3; q3l += accP3*accP3;
    }

    // block-reduce the 4 stats, one atomic each per block
    #pragma unroll
    for (int off = 32; off > 0; off >>= 1) {
        s2l += __shfl_down(s2l, off, 64);
        q2l += __shfl_down(q2l, off, 64);
        s3l += __shfl_down(s3l, off, 64);
        q3l += __shfl_down(q3l, off, 64);
    }
    __shared__ float red[4][4];
    int lane = tid & 63, wid = tid >> 6;
    __syncthreads();
    if (lane == 0) { red[0][wid] = s2l; red[1][wid] = q2l; red[2][wid] = s3l; red[3][wid] = q3l; }
    __syncthreads();
    if (tid == 0) {
        #pragma unroll
        for (int j = 0; j < 4; ++j)
            atomicAdd(&stats2[j], red[j][0] + red[j][1] + red[j][2] + red[j][3]);
    }
}

// ---------- kernel 5: finalize scale/shift BN params ----------
__global__ void k5_fin2(const float* __restrict__ stats2,
                        const float* __restrict__ gs, const float* __restrict__ bs,
                        const float* __restrict__ gt, const float* __restrict__ bt,
                        float* __restrict__ ab2) {
    if (threadIdx.x == 0) {
        float n = (float)NPER;
        float m2 = stats2[0] / n, v2 = stats2[1] / n - m2*m2;
        float a2 = gs[0] * rsqrtf(v2 + 1e-5f);
        ab2[0] = a2; ab2[1] = bs[0] - m2*a2;
        float m3 = stats2[2] / n, v3 = stats2[3] / n - m3*m3;
        float a3 = gt[0] * rsqrtf(v3 + 1e-5f);
        ab2[2] = a3; ab2[3] = bt[0] - m3*a3;
    }
}

// ---------- kernel 6: epilogue ----------
__global__ __launch_bounds__(256)
void k6_final(const float* __restrict__ c2, const float* __restrict__ c3,
              const float* __restrict__ ab2, float* __restrict__ out) {
    int i = blockIdx.x * blockDim.x + threadIdx.x;
    if (i < NPER) {
        float ls = fmaf(ab2[0], c2[i], ab2[1]);
        out[i] = sigmoidf_(ls + 2.f) + 1e-4f;                 // scale
        out[NPER + i] = fmaf(ab2[2], c3[i], ab2[3]);          // shift
    }
}

// ---------- launch ----------
extern "C" void kernel_launch(void* const* d_in, const int* in_sizes, int n_in,
                              void* d_out, int out_size, void* d_ws, size_t ws_size,
                              hipStream_t stream) {
    const float* in          = (const float*)d_in[0];
    const float* w_gate      = (const float*)d_in[1];
    const float* gamma_gate  = (const float*)d_in[2];
    const float* beta_gate   = (const float*)d_in[3];
    const float* w_scale     = (const float*)d_in[4];
    const float* gamma_scale = (const float*)d_in[5];
    const float* beta_scale  = (const float*)d_in[6];
    const float* w_shift     = (const float*)d_in[7];
    const float* gamma_shift = (const float*)d_in[8];
    const float* beta_shift  = (const float*)d_in[9];
    const int*   rev         = (const int*)d_in[10];

    float* ws   = (float*)d_ws;
    float* hbuf = ws;
    float* c2   = ws + C2_OFF;
    float* c3   = ws + C3_OFF;
    float* s1   = ws + S1_OFF;
    float* ab1  = ws + AB1_OFF;
    float* s2   = ws + S2_OFF;
    float* ab2  = ws + AB2_OFF;
    float* out  = (float*)d_out;

    hipMemsetAsync(s1, 0, (64 + 64 + 4 + 4) * sizeof(float), stream);

    k1_gates_stats<<<dim3(THW/256, 32, TB), 256, 0, stream>>>(in, w_gate, s1);
    k2_fin1<<<1, 32, 0, stream>>>(s1, gamma_gate, beta_gate, ab1);
    k3_scan<<<dim3(THW/256, HCN, TB), 256, 0, stream>>>(in, w_gate, ab1, rev, hbuf);
    k4_conv23<<<dim3(100, (TT + TCH - 1)/TCH, TB), 256, 0, stream>>>(hbuf, w_scale, w_shift, c2, c3, s2);
    k5_fin2<<<1, 64, 0, stream>>>(s2, gamma_scale, beta_scale, gamma_shift, beta_shift, ab2);
    k6_final<<<(NPER + 255)/256, 256, 0, stream>>>(c2, c3, ab2, out);
}

// Round 3
// 355.530 us; speedup vs baseline: 1.9652x; 1.1656x over previous
//
#include <hip/hip_runtime.h>
#include <math.h>

// Problem constants
#define TB 2
#define TT 31
#define TH 160
#define TW 160
#define THW (TH*TW)            // 25600
#define NPER (TB*TT*THW)       // 1,587,200
#define HCN 16
#define TCH 8                  // t-chunk for k4
#define LS 24                  // LDS row stride (18 used) -> perfect 2-way banking

// Workspace layout (floats)
#define H_ELEMS (TB*HCN*TT*THW)
#define C2_OFF  H_ELEMS
#define C3_OFF  (C2_OFF + NPER)
#define S1_OFF  (C3_OFF + NPER)
#define AB1_OFF (S1_OFF + 64)
#define S2_OFF  (AB1_OFF + 64)
#define AB2_OFF (S2_OFF + 4)

__device__ __forceinline__ float sigmoidf_(float x) {
    return 1.f / (1.f + expf(-x));
}

// ---------- kernel 1: conv1 per-channel sum/sumsq, LDS-tiled ----------
// grid: (32 c, 100 tiles, 2 b), block 256 = 16x16
__global__ __launch_bounds__(256)
void k1_gates_stats(const float* __restrict__ in, const float* __restrict__ wg,
                    float* __restrict__ stats) {
    __shared__ float pl[18*LS];
    int c = blockIdx.x, tile = blockIdx.y, b = blockIdx.z;
    int ty0 = (tile / 10) * 16, tx0 = (tile % 10) * 16;
    int tid = threadIdx.x;
    int ly = tid >> 4, lx = tid & 15;

    float wc[27];
    #pragma unroll
    for (int i = 0; i < 27; ++i) wc[i] = wg[c*27 + i];

    // staging coords (18x18 halo plane)
    int i0 = tid, i1 = tid + 256;
    int py0 = i0 / 18, px0 = i0 % 18;
    int py1 = i1 / 18, px1 = i1 % 18;
    int gy0 = ty0 + py0 - 1, gx0 = tx0 + px0 - 1;
    int gy1 = ty0 + py1 - 1, gx1 = tx0 + px1 - 1;
    bool ok0 = (gy0 >= 0 && gy0 < TH && gx0 >= 0 && gx0 < TW);
    bool ok1 = (i1 < 324) && (gy1 >= 0 && gy1 < TH && gx1 >= 0 && gx1 < TW);
    long off0 = (long)gy0 * TW + gx0;
    long off1 = (long)gy1 * TW + gx1;

    float pm[9], pc_[9], pn[9];
    #pragma unroll
    for (int i = 0; i < 9; ++i) pm[i] = 0.f;

    // stage plane 0, read pc_
    {
        long base = (long)(b*TT + 0) * THW;
        float r0 = ok0 ? in[base + off0] : 0.f;
        float r1 = ok1 ? in[base + off1] : 0.f;
        pl[py0*LS + px0] = r0;
        if (i1 < 324) pl[py1*LS + px1] = r1;
        __syncthreads();
        #pragma unroll
        for (int ky = 0; ky < 3; ++ky)
            #pragma unroll
            for (int kx = 0; kx < 3; ++kx)
                pc_[ky*3 + kx] = pl[(ly + ky)*LS + (lx + kx)];
    }
    // prefetch plane 1
    float r0, r1;
    {
        long base = (long)(b*TT + 1) * THW;
        r0 = ok0 ? in[base + off0] : 0.f;
        r1 = ok1 ? in[base + off1] : 0.f;
    }

    float s = 0.f, sq = 0.f;
    for (int t = 0; t < TT; ++t) {
        __syncthreads();                    // taps of previous plane consumed
        pl[py0*LS + px0] = r0;
        if (i1 < 324) pl[py1*LS + px1] = r1;
        // prefetch plane t+2
        if (t + 2 <= TT - 1) {
            long base = (long)(b*TT + t + 2) * THW;
            r0 = ok0 ? in[base + off0] : 0.f;
            r1 = ok1 ? in[base + off1] : 0.f;
        } else { r0 = 0.f; r1 = 0.f; }
        __syncthreads();
        #pragma unroll
        for (int ky = 0; ky < 3; ++ky)
            #pragma unroll
            for (int kx = 0; kx < 3; ++kx)
                pn[ky*3 + kx] = pl[(ly + ky)*LS + (lx + kx)];

        float v = 0.f;
        #pragma unroll
        for (int i = 0; i < 9; ++i) v = fmaf(wc[i],      pm[i], v);
        #pragma unroll
        for (int i = 0; i < 9; ++i) v = fmaf(wc[9 + i],  pc_[i], v);
        #pragma unroll
        for (int i = 0; i < 9; ++i) v = fmaf(wc[18 + i], pn[i], v);
        s += v; sq += v*v;
        #pragma unroll
        for (int i = 0; i < 9; ++i) { pm[i] = pc_[i]; pc_[i] = pn[i]; }
    }

    #pragma unroll
    for (int off = 32; off > 0; off >>= 1) {
        s  += __shfl_down(s,  off, 64);
        sq += __shfl_down(sq, off, 64);
    }
    __shared__ float ls[4], lq[4];
    int lane = tid & 63, wid = tid >> 6;
    if (lane == 0) { ls[wid] = s; lq[wid] = sq; }
    __syncthreads();
    if (tid == 0) {
        atomicAdd(&stats[c],      ls[0]+ls[1]+ls[2]+ls[3]);
        atomicAdd(&stats[32 + c], lq[0]+lq[1]+lq[2]+lq[3]);
    }
}

// ---------- kernel 2: finalize gate BN params ----------
__global__ void k2_fin1(const float* __restrict__ stats, const float* __restrict__ gamma,
                        const float* __restrict__ beta, float* __restrict__ ab) {
    int c = threadIdx.x;
    if (c < 32) {
        float n = (float)NPER;
        float mean = stats[c] / n;
        float var  = stats[32 + c] / n - mean*mean;
        float a = gamma[c] * rsqrtf(var + 1e-5f);
        ab[c]      = a;
        ab[32 + c] = beta[c] - mean * a;
    }
}

// ---------- kernel 3: conv1 recompute + BN + activations + scan, LDS-tiled ----------
// grid: (16 c, 100 tiles, 2 b), block 256 = 16x16
__global__ __launch_bounds__(256)
void k3_scan(const float* __restrict__ in, const float* __restrict__ wg,
             const float* __restrict__ ab, const int* __restrict__ rev_p,
             float* __restrict__ hbuf) {
    __shared__ float pl[18*LS];
    int c = blockIdx.x, tile = blockIdx.y, b = blockIdx.z;
    int ty0 = (tile / 10) * 16, tx0 = (tile % 10) * 16;
    int tid = threadIdx.x;
    int ly = tid >> 4, lx = tid & 15;
    int y = ty0 + ly, x = tx0 + lx;

    float wz[27], wf[27];
    #pragma unroll
    for (int i = 0; i < 27; ++i) { wz[i] = wg[c*27 + i]; wf[i] = wg[(c + 16)*27 + i]; }
    float az = ab[c],      bz = ab[32 + c];
    float af = ab[c + 16], bf = ab[32 + c + 16];
    int rev = rev_p[0];

    int i0 = tid, i1 = tid + 256;
    int py0 = i0 / 18, px0 = i0 % 18;
    int py1 = i1 / 18, px1 = i1 % 18;
    int gy0 = ty0 + py0 - 1, gx0 = tx0 + px0 - 1;
    int gy1 = ty0 + py1 - 1, gx1 = tx0 + px1 - 1;
    bool ok0 = (gy0 >= 0 && gy0 < TH && gx0 >= 0 && gx0 < TW);
    bool ok1 = (i1 < 324) && (gy1 >= 0 && gy1 < TH && gx1 >= 0 && gx1 < TW);
    long off0 = (long)gy0 * TW + gx0;
    long off1 = (long)gy1 * TW + gx1;

    float h = 0.f;
    float pm[9], pc_[9], pn[9];
    long hbase = ((long)(b*HCN + c)) * TT * THW + (long)y*TW + x;

    if (!rev) {
        #pragma unroll
        for (int i = 0; i < 9; ++i) pm[i] = 0.f;
        {
            long base = (long)(b*TT + 0) * THW;
            float r0 = ok0 ? in[base + off0] : 0.f;
            float r1 = ok1 ? in[base + off1] : 0.f;
            pl[py0*LS + px0] = r0;
            if (i1 < 324) pl[py1*LS + px1] = r1;
            __syncthreads();
            #pragma unroll
            for (int ky = 0; ky < 3; ++ky)
                #pragma unroll
                for (int kx = 0; kx < 3; ++kx)
                    pc_[ky*3 + kx] = pl[(ly + ky)*LS + (lx + kx)];
        }
        float r0, r1;
        {
            long base = (long)(b*TT + 1) * THW;
            r0 = ok0 ? in[base + off0] : 0.f;
            r1 = ok1 ? in[base + off1] : 0.f;
        }
        for (int t = 0; t < TT; ++t) {
            __syncthreads();
            pl[py0*LS + px0] = r0;
            if (i1 < 324) pl[py1*LS + px1] = r1;
            if (t + 2 <= TT - 1) {
                long base = (long)(b*TT + t + 2) * THW;
                r0 = ok0 ? in[base + off0] : 0.f;
                r1 = ok1 ? in[base + off1] : 0.f;
            } else { r0 = 0.f; r1 = 0.f; }
            __syncthreads();
            #pragma unroll
            for (int ky = 0; ky < 3; ++ky)
                #pragma unroll
                for (int kx = 0; kx < 3; ++kx)
                    pn[ky*3 + kx] = pl[(ly + ky)*LS + (lx + kx)];

            float vz = 0.f, vf = 0.f;
            #pragma unroll
            for (int i = 0; i < 9; ++i) { vz = fmaf(wz[i],      pm[i], vz); vf = fmaf(wf[i],      pm[i], vf); }
            #pragma unroll
            for (int i = 0; i < 9; ++i) { vz = fmaf(wz[9 + i],  pc_[i], vz); vf = fmaf(wf[9 + i],  pc_[i], vf); }
            #pragma unroll
            for (int i = 0; i < 9; ++i) { vz = fmaf(wz[18 + i], pn[i], vz); vf = fmaf(wf[18 + i], pn[i], vf); }
            float z = tanhf(fmaf(az, vz, bz));
            float f = sigmoidf_(fmaf(af, vf, bf));
            h = f*h + (1.f - f)*z;
            hbuf[hbase + (long)t * THW] = h;
            #pragma unroll
            for (int i = 0; i < 9; ++i) { pm[i] = pc_[i]; pc_[i] = pn[i]; }
        }
    } else {
        #pragma unroll
        for (int i = 0; i < 9; ++i) pn[i] = 0.f;
        {
            long base = (long)(b*TT + (TT - 1)) * THW;
            float r0 = ok0 ? in[base + off0] : 0.f;
            float r1 = ok1 ? in[base + off1] : 0.f;
            pl[py0*LS + px0] = r0;
            if (i1 < 324) pl[py1*LS + px1] = r1;
            __syncthreads();
            #pragma unroll
            for (int ky = 0; ky < 3; ++ky)
                #pragma unroll
                for (int kx = 0; kx < 3; ++kx)
                    pc_[ky*3 + kx] = pl[(ly + ky)*LS + (lx + kx)];
        }
        float r0, r1;
        {
            long base = (long)(b*TT + (TT - 2)) * THW;
            r0 = ok0 ? in[base + off0] : 0.f;
            r1 = ok1 ? in[base + off1] : 0.f;
        }
        for (int t = TT - 1; t >= 0; --t) {
            __syncthreads();
            pl[py0*LS + px0] = r0;
            if (i1 < 324) pl[py1*LS + px1] = r1;
            if (t - 2 >= 0) {
                long base = (long)(b*TT + t - 2) * THW;
                r0 = ok0 ? in[base + off0] : 0.f;
                r1 = ok1 ? in[base + off1] : 0.f;
            } else { r0 = 0.f; r1 = 0.f; }
            __syncthreads();
            #pragma unroll
            for (int ky = 0; ky < 3; ++ky)
                #pragma unroll
                for (int kx = 0; kx < 3; ++kx)
                    pm[ky*3 + kx] = pl[(ly + ky)*LS + (lx + kx)];

            float vz = 0.f, vf = 0.f;
            #pragma unroll
            for (int i = 0; i < 9; ++i) { vz = fmaf(wz[i],      pm[i], vz); vf = fmaf(wf[i],      pm[i], vf); }
            #pragma unroll
            for (int i = 0; i < 9; ++i) { vz = fmaf(wz[9 + i],  pc_[i], vz); vf = fmaf(wf[9 + i],  pc_[i], vf); }
            #pragma unroll
            for (int i = 0; i < 9; ++i) { vz = fmaf(wz[18 + i], pn[i], vz); vf = fmaf(wf[18 + i], pn[i], vf); }
            float z = tanhf(fmaf(az, vz, bz));
            float f = sigmoidf_(fmaf(af, vf, bf));
            h = f*h + (1.f - f)*z;
            hbuf[hbase + (long)t * THW] = h;
            #pragma unroll
            for (int i = 0; i < 9; ++i) { pn[i] = pc_[i]; pc_[i] = pm[i]; }
        }
    }
}

// ---------- kernel 4: LDS-tiled conv2+conv3 with reg prefetch ----------
// grid: (100 tiles, 4 t-chunks, 2 b), block 256 = 16x16
__global__ __launch_bounds__(256)
void k4_conv23(const float* __restrict__ hbuf, const float* __restrict__ wsc,
               const float* __restrict__ wsh, float* __restrict__ c2,
               float* __restrict__ c3, float* __restrict__ stats2) {
    __shared__ float pl2[18*LS];
    __shared__ float pl3[18*LS];

    int b  = blockIdx.z;
    int t0 = blockIdx.y * TCH;
    int t1 = min(t0 + TCH - 1, TT - 1);
    int tile = blockIdx.x;
    int ty0 = (tile / 10) * 16, tx0 = (tile % 10) * 16;
    int tid = threadIdx.x;
    int ly = tid >> 4, lx = tid & 15;
    int y = ty0 + ly, x = tx0 + lx;

    int ts = max(t0 - 1, 0), te = min(t1 + 1, TT - 1);
    int nplanes = (te - ts + 1) * 8;

    int i0 = tid, i1 = tid + 256;
    int py0 = i0 / 18, px0 = i0 % 18;
    int py1 = i1 / 18, px1 = i1 % 18;
    int gy0 = ty0 + py0 - 1, gx0 = tx0 + px0 - 1;
    int gy1 = ty0 + py1 - 1, gx1 = tx0 + px1 - 1;
    bool ok0 = (gy0 >= 0 && gy0 < TH && gx0 >= 0 && gx0 < TW);
    bool ok1 = (i1 < 324) && (gy1 >= 0 && gy1 < TH && gx1 >= 0 && gx1 < TW);
    long off0 = (long)gy0 * TW + gx0;
    long off1 = (long)gy1 * TW + gx1;

    float accP2 = 0.f, accC2 = 0.f, accN2 = 0.f;
    float accP3 = 0.f, accC3 = 0.f, accN3 = 0.f;
    float s2l = 0.f, q2l = 0.f, s3l = 0.f, q3l = 0.f;

    // prefetch plane 0
    float r2a, r2b, r3a, r3b;
    {
        long b2 = ((long)((b*HCN + 0)*TT + ts)) * THW;
        long b3 = ((long)((b*HCN + 8)*TT + ts)) * THW;
        r2a = ok0 ? hbuf[b2 + off0] : 0.f;
        r2b = ok1 ? hbuf[b2 + off1] : 0.f;
        r3a = ok0 ? hbuf[b3 + off0] : 0.f;
        r3b = ok1 ? hbuf[b3 + off1] : 0.f;
    }

    for (int p = 0; p < nplanes; ++p) {
        int c = p & 7;
        int t_in = ts + (p >> 3);
        __syncthreads();
        pl2[py0*LS + px0] = r2a;
        if (i1 < 324) pl2[py1*LS + px1] = r2b;
        pl3[py0*LS + px0] = r3a;
        if (i1 < 324) pl3[py1*LS + px1] = r3b;
        if (p + 1 < nplanes) {
            int cn = (p + 1) & 7, tn = ts + ((p + 1) >> 3);
            long b2 = ((long)((b*HCN + cn)*TT + tn)) * THW;
            long b3 = ((long)((b*HCN + 8 + cn)*TT + tn)) * THW;
            r2a = ok0 ? hbuf[b2 + off0] : 0.f;
            r2b = ok1 ? hbuf[b2 + off1] : 0.f;
            r3a = ok0 ? hbuf[b3 + off0] : 0.f;
            r3b = ok1 ? hbuf[b3 + off1] : 0.f;
        }
        __syncthreads();

        float t2[9], t3[9];
        #pragma unroll
        for (int ky = 0; ky < 3; ++ky)
            #pragma unroll
            for (int kx = 0; kx < 3; ++kx) {
                int li = (ly + ky)*LS + (lx + kx);
                t2[ky*3 + kx] = pl2[li];
                t3[ky*3 + kx] = pl3[li];
            }
        const float* w2 = wsc + c*27;
        const float* w3 = wsh + c*27;
        #pragma unroll
        for (int i = 0; i < 9; ++i) {
            accN2 = fmaf(w2[i],      t2[i], accN2);
            accC2 = fmaf(w2[9 + i],  t2[i], accC2);
            accP2 = fmaf(w2[18 + i], t2[i], accP2);
            accN3 = fmaf(w3[i],      t3[i], accN3);
            accC3 = fmaf(w3[9 + i],  t3[i], accC3);
            accP3 = fmaf(w3[18 + i], t3[i], accP3);
        }

        if (c == 7) {
            int t_out = t_in - 1;
            if (t_out >= t0 && t_out <= t1) {
                long oidx = ((long)(b*TT + t_out)) * THW + (long)y*TW + x;
                c2[oidx] = accP2; c3[oidx] = accP3;
                s2l += accP2; q2l += accP2*accP2;
                s3l += accP3; q3l += accP3*accP3;
            }
            accP2 = accC2; accC2 = accN2; accN2 = 0.f;
            accP3 = accC3; accC3 = accN3; accN3 = 0.f;
        }
    }
    if (t1 == TT - 1) {
        long oidx = ((long)(b*TT + (TT - 1))) * THW + (long)y*TW + x;
        c2[oidx] = accP2; c3[oidx] = accP3;
        s2l += accP2; q2l += accP2*accP2;
        s3l += accP3; q3l += accP3*accP3;
    }

    #pragma unroll
    for (int off = 32; off > 0; off >>= 1) {
        s2l += __shfl_down(s2l, off, 64);
        q2l += __shfl_down(q2l, off, 64);
        s3l += __shfl_down(s3l, off, 64);
        q3l += __shfl_down(q3l, off, 64);
    }
    __shared__ float red[4][4];
    int lane = tid & 63, wid = tid >> 6;
    __syncthreads();
    if (lane == 0) { red[0][wid] = s2l; red[1][wid] = q2l; red[2][wid] = s3l; red[3][wid] = q3l; }
    __syncthreads();
    if (tid == 0) {
        #pragma unroll
        for (int j = 0; j < 4; ++j)
            atomicAdd(&stats2[j], red[j][0] + red[j][1] + red[j][2] + red[j][3]);
    }
}

// ---------- kernel 5: finalize scale/shift BN params ----------
__global__ void k5_fin2(const float* __restrict__ stats2,
                        const float* __restrict__ gs, const float* __restrict__ bs,
                        const float* __restrict__ gt, const float* __restrict__ bt,
                        float* __restrict__ ab2) {
    if (threadIdx.x == 0) {
        float n = (float)NPER;
        float m2 = stats2[0] / n, v2 = stats2[1] / n - m2*m2;
        float a2 = gs[0] * rsqrtf(v2 + 1e-5f);
        ab2[0] = a2; ab2[1] = bs[0] - m2*a2;
        float m3 = stats2[2] / n, v3 = stats2[3] / n - m3*m3;
        float a3 = gt[0] * rsqrtf(v3 + 1e-5f);
        ab2[2] = a3; ab2[3] = bt[0] - m3*a3;
    }
}

// ---------- kernel 6: epilogue, float4 ----------
__global__ __launch_bounds__(256)
void k6_final(const float4* __restrict__ c2, const float4* __restrict__ c3,
              const float* __restrict__ ab2, float4* __restrict__ out) {
    int i = blockIdx.x * blockDim.x + threadIdx.x;
    if (i < NPER/4) {
        float a2 = ab2[0], b2 = ab2[1], a3 = ab2[2], b3 = ab2[3];
        float4 v2 = c2[i], v3 = c3[i];
        float4 sc, sh;
        sc.x = sigmoidf_(fmaf(a2, v2.x, b2) + 2.f) + 1e-4f;
        sc.y = sigmoidf_(fmaf(a2, v2.y, b2) + 2.f) + 1e-4f;
        sc.z = sigmoidf_(fmaf(a2, v2.z, b2) + 2.f) + 1e-4f;
        sc.w = sigmoidf_(fmaf(a2, v2.w, b2) + 2.f) + 1e-4f;
        sh.x = fmaf(a3, v3.x, b3);
        sh.y = fmaf(a3, v3.y, b3);
        sh.z = fmaf(a3, v3.z, b3);
        sh.w = fmaf(a3, v3.w, b3);
        out[i] = sc;
        out[NPER/4 + i] = sh;
    }
}

// ---------- launch ----------
extern "C" void kernel_launch(void* const* d_in, const int* in_sizes, int n_in,
                              void* d_out, int out_size, void* d_ws, size_t ws_size,
                              hipStream_t stream) {
    const float* in          = (const float*)d_in[0];
    const float* w_gate      = (const float*)d_in[1];
    const float* gamma_gate  = (const float*)d_in[2];
    const float* beta_gate   = (const float*)d_in[3];
    const float* w_scale     = (const float*)d_in[4];
    const float* gamma_scale = (const float*)d_in[5];
    const float* beta_scale  = (const float*)d_in[6];
    const float* w_shift     = (const float*)d_in[7];
    const float* gamma_shift = (const float*)d_in[8];
    const float* beta_shift  = (const float*)d_in[9];
    const int*   rev         = (const int*)d_in[10];

    float* ws   = (float*)d_ws;
    float* hbuf = ws;
    float* c2   = ws + C2_OFF;
    float* c3   = ws + C3_OFF;
    float* s1   = ws + S1_OFF;
    float* ab1  = ws + AB1_OFF;
    float* s2   = ws + S2_OFF;
    float* ab2  = ws + AB2_OFF;
    float* out  = (float*)d_out;

    hipMemsetAsync(s1, 0, (64 + 64 + 4 + 4) * sizeof(float), stream);

    k1_gates_stats<<<dim3(32, 100, TB), 256, 0, stream>>>(in, w_gate, s1);
    k2_fin1<<<1, 32, 0, stream>>>(s1, gamma_gate, beta_gate, ab1);
    k3_scan<<<dim3(HCN, 100, TB), 256, 0, stream>>>(in, w_gate, ab1, rev, hbuf);
    k4_conv23<<<dim3(100, (TT + TCH - 1)/TCH, TB), 256, 0, stream>>>(hbuf, w_scale, w_shift, c2, c3, s2);
    k5_fin2<<<1, 64, 0, stream>>>(s2, gamma_scale, beta_scale, gamma_shift, beta_shift, ab2);
    k6_final<<<(NPER/4 + 255)/256, 256, 0, stream>>>((const float4*)c2, (const float4*)c3, ab2, (float4*)out);
}